// Round 5
// baseline (1329.048 us; speedup 1.0000x reference)
//
#include <hip/hip_runtime.h>
#include <hip/hip_fp16.h>
#include <hip/hip_cooperative_groups.h>
#include <cmath>

namespace cg = cooperative_groups;

#define LNUM 6
#define DM   1152
#define DHEAD 256
#define NH   4
#define FF   6912
#define VOC  65536
#define HIST 4095
#define SEQ  4096
#define EPSV 1e-6f
#define NB   256

// ---- coop-path ws float offsets ----
#define QKV_O 0            // [6][1536]
#define AP_O  9216         // [6][1152]
#define DP_O  16128        // [6][1152]
#define GU_O  23040        // [6][13824]
#define ZEND  105984
#define HIN_O 105984       // [6][1152]
#define HM_O  112896       // [6][1152]
#define POP_O 119808       // [128][1024]
#define SPS_O 250880       // [128][4]
#define LGP_O 251392       // [6][65536]
#define AMV_O 775680       // [128]
#define AMI_O 775936       // [128]

// ---- fallback-path (round-2 verbatim) ws float offsets ----
#define F_QKV_O 0
#define F_AP_O  9216
#define F_DP_O  16128
#define F_ZEND  23040
#define F_POP_O 23040      // [128][1024]
#define F_SPS_O 154112     // [128][4]
#define F_GUP_O 154624     // [16][13824]
#define F_LGP_O 375808     // [6][65536]
#define F_HIN_O 769024     // [6][1152]
#define F_HM_O  775936     // [6][1152]
#define F_AMV_O 782848     // [128]
#define F_AMI_O 782976     // [128]

struct P {
    const int* ids; const int* aflag;
    const float* kc; const float* vc;
    const int* tbl; const float* esc; const float* ezp;
    const float* w_in; const float* w_qn; const float* w_kn;
    const float* Wq; const float* Wk; const float* Wv; const float* Wo;
    const float* w_pa; const float* w_pf; const float* w_pof;
    const float* Wg; const float* Wu; const float* Wd;
    const float* w_fin; const float* Wlm;
    float* keys; float* vals; float* tok; float* ws;
};

__device__ __forceinline__ float bsum(float v, float* red4) {
#pragma unroll
    for (int off = 32; off; off >>= 1) v += __shfl_xor(v, off);
    int t = threadIdx.x;
    if ((t & 63) == 0) red4[t >> 6] = v;
    __syncthreads();
    float r = red4[0] + red4[1] + red4[2] + red4[3];
    __syncthreads();
    return r;
}

// ==================== cooperative mega kernel (NB=256, grid-stride units) ====================
__global__ __launch_bounds__(256) void mega(P p) {
    cg::grid_group gg = cg::this_grid();
    __shared__ float sm[8192];
    const int t = threadIdx.x, bid = blockIdx.x;
    float* ws = p.ws;

    // ---------- phase 0: zero accumulators + embed + cache copies ----------
    {
        for (int g = bid * 256 + t; g < ZEND; g += NB * 256) ws[g] = 0.f;
        if (bid == 0) {
            int tk = p.ids[0];
            float sc = p.esc[tk], z = p.ezp[tk];
            const int* row = p.tbl + (size_t)tk * DM;
            for (int i = t; i < DM; i += 256) ws[HIN_O + i] = (float)row[i] * sc + z;
        }
        for (int rr = 0; rr < 6; ++rr) {       // keys: 1536 rows, 6/block
            int row = bid * 6 + rr;
            const float* src = p.kc + (size_t)row * HIST;
            float* dst = p.keys + (size_t)row * SEQ;
            for (int s = t; s < HIST; s += 256) dst[s] = src[s];
        }
        for (int rr = 0; rr < 24; ++rr) {      // vals: 24570 rows, 96/block, float4
            int r = bid * 96 + rr * 4 + (t >> 6);
            if (r < LNUM * HIST) {
                int l = r / HIST, sI = r - l * HIST;
                ((float4*)(p.vals + ((size_t)l * SEQ + sI) * DHEAD))[t & 63] =
                    ((const float4*)(p.vc + (size_t)r * DHEAD))[t & 63];
            }
        }
    }
    gg.sync();

    for (int l = 0; l < LNUM; ++l) {
        float* QKV = ws + QKV_O + l * 1536;
        float* AP  = ws + AP_O + l * DM;
        float* DP  = ws + DP_O + l * DM;
        float* GU  = ws + GU_O + l * 13824;
        float* HIN = ws + HIN_O + l * DM;
        float* HM  = ws + HM_O + l * DM;
        float* POP = ws + POP_O;
        float* SPS = ws + SPS_O;
        float* keys_l = p.keys + (size_t)l * DHEAD * SEQ;
        float* vals_l = p.vals + (size_t)l * SEQ * DHEAD;

        // ---------- qkv phase: prefix + 384 GEMV units ----------
        {
            float* xv = sm; float* red4 = sm + 1280;
            if (l == 0) {
                for (int i = t; i < DM; i += 256) xv[i] = ws[HIN_O + i];
                __syncthreads();
            } else {
                const float* hprev = ws + HM_O + (l - 1) * DM;
                const float* dprev = ws + DP_O + (l - 1) * DM;
                const float* wpof = p.w_pof + (l - 1) * DM;
                float ss = 0.f;
                for (int i = t; i < DM; i += 256) { float d = dprev[i]; ss += d * d; }
                ss = bsum(ss, red4);
                float inv = 1.f / sqrtf(ss / DM + EPSV);
                for (int i = t; i < DM; i += 256)
                    xv[i] = hprev[i] + wpof[i] * dprev[i] * inv;
                __syncthreads();
            }
            if (bid == 0) for (int i = t; i < DM; i += 256) HIN[i] = xv[i];
            float ss = 0.f;
            for (int i = t; i < DM; i += 256) { float v = xv[i]; ss += v * v; }
            ss = bsum(ss, red4);
            float inv = 1.f / sqrtf(ss / DM + EPSV);
            const float* w_in = p.w_in + l * DM;
            for (int i = t; i < DM; i += 256) xv[i] = w_in[i] * xv[i] * inv;
            __syncthreads();
            for (int u = bid; u < 384; u += NB) {
                int cgp = u % 6, kc = u / 6;
                int j = cgp * 256 + t;
                const float* W; int jj, ncol;
                if (j < 1024)      { W = p.Wq + (size_t)l * DM * 1024; jj = j;        ncol = 1024; }
                else if (j < 1280) { W = p.Wk + (size_t)l * DM * 256;  jj = j - 1024; ncol = 256; }
                else               { W = p.Wv + (size_t)l * DM * 256;  jj = j - 1280; ncol = 256; }
                int i0 = kc * 18;
                float acc = 0.f;
#pragma unroll
                for (int ii = 0; ii < 18; ++ii)
                    acc += xv[i0 + ii] * W[(size_t)(i0 + ii) * ncol + jj];
                atomicAdd(&QKV[j], acc);
            }
        }
        gg.sync();

        // ---------- attn phase (blocks 0..127, 32 positions each) ----------
        if (bid < 128) {
            float* lq = sm;
            float* lqf = sm + 1024;
            float* lkn = sm + 2048;
            float* lkf = sm + 2304;
            float* lv  = sm + 2560;
            float* lp  = sm + 2816;
            float* red4 = sm + 2944;
            float* scred = sm + 3072;
            float* pvred = sm + 4096;
            int s0 = bid * 32;
            bool lastb = (bid == 127);
            float base = ((l % 6) != 5) ? 1000000.f : 10000.f;
            int jm = t & 127;
            float theta = powf(base, -(float)(2 * jm) / 256.f);
            float ang = 4095.f * theta;
            float c = __half2float(__float2half(cosf(ang)));
            float s = __half2float(__float2half(sinf(ang)));
            for (int h = 0; h < NH; ++h) lq[h * 256 + t] = QKV[h * 256 + t];
            lkn[t] = QKV[1024 + t];
            lv[t]  = QKV[1280 + t];
            __syncthreads();
            const float* wqn = p.w_qn + l * DHEAD;
            const float* wkn = p.w_kn + l * DHEAD;
            for (int h = 0; h < NH; ++h) {
                float v = lq[h * 256 + t];
                float ss = bsum(v * v, red4);
                float inv = 1.f / sqrtf(ss / 256.f + EPSV);
                float qn = wqn[t] * v * inv;
                lq[h * 256 + t] = qn;
                __syncthreads();
                float partner = (t < 128) ? -lq[h * 256 + t + 128] : lq[h * 256 + t - 128];
                lqf[h * 256 + t] = qn * c + partner * s;
            }
            {
                float v = lkn[t];
                float ss = bsum(v * v, red4);
                float inv = 1.f / sqrtf(ss / 256.f + EPSV);
                float kn = wkn[t] * v * inv;
                lkn[t] = kn;
                __syncthreads();
                float partner = (t < 128) ? -lkn[t + 128] : lkn[t - 128];
                lkf[t] = kn * c + partner * s;
            }
            __syncthreads();
            if (lastb) {
                keys_l[(size_t)t * SEQ + (SEQ - 1)] = lkf[t];
                vals_l[(size_t)(SEQ - 1) * DHEAD + t] = lv[t];
            }
            int sl = t & 31, dc = t >> 5;
            int sg = s0 + sl;
            bool self = lastb && (sl == 31);
            float a0 = 0, a1 = 0, a2 = 0, a3 = 0;
#pragma unroll 4
            for (int dd = 0; dd < 32; ++dd) {
                int d = dc * 32 + dd;
                float kv = self ? lkf[d] : keys_l[(size_t)d * SEQ + sg];
                a0 += lqf[d] * kv; a1 += lqf[256 + d] * kv;
                a2 += lqf[512 + d] * kv; a3 += lqf[768 + d] * kv;
            }
            scred[dc * 128 + sl]      = a0;
            scred[dc * 128 + 32 + sl] = a1;
            scred[dc * 128 + 64 + sl] = a2;
            scred[dc * 128 + 96 + sl] = a3;
            __syncthreads();
            if (t < 32) {
                int af = p.aflag[0];
                float mk = (s0 + t > 0) ? -128.f * (float)af : 0.f;
                for (int h = 0; h < NH; ++h) {
                    float sc_ = 0.f;
#pragma unroll
                    for (int d8 = 0; d8 < 8; ++d8) sc_ += scred[d8 * 128 + h * 32 + t];
                    lp[h * 32 + t] = expf(sc_ + mk);
                }
            }
            __syncthreads();
            if (t < NH) {
                float su = 0.f;
                for (int i = 0; i < 32; ++i) su += lp[t * 32 + i];
                SPS[bid * NH + t] = su;
            }
            int d4 = t & 63, sr = t >> 6;
            float4 ac0 = {0,0,0,0}, ac1 = {0,0,0,0}, ac2 = {0,0,0,0}, ac3 = {0,0,0,0};
#pragma unroll
            for (int ss_ = 0; ss_ < 8; ++ss_) {
                int sI = sr * 8 + ss_;
                float4 v;
                if (lastb && sI == 31) v = ((float4*)lv)[d4];
                else v = ((const float4*)(vals_l + (size_t)(s0 + sI) * DHEAD))[d4];
                float p0 = lp[sI], p1 = lp[32 + sI], p2 = lp[64 + sI], p3 = lp[96 + sI];
                ac0.x += p0 * v.x; ac0.y += p0 * v.y; ac0.z += p0 * v.z; ac0.w += p0 * v.w;
                ac1.x += p1 * v.x; ac1.y += p1 * v.y; ac1.z += p1 * v.z; ac1.w += p1 * v.w;
                ac2.x += p2 * v.x; ac2.y += p2 * v.y; ac2.z += p2 * v.z; ac2.w += p2 * v.w;
                ac3.x += p3 * v.x; ac3.y += p3 * v.y; ac3.z += p3 * v.z; ac3.w += p3 * v.w;
            }
            ((float4*)(pvred + sr * 1024 + 0))[d4]   = ac0;
            ((float4*)(pvred + sr * 1024 + 256))[d4] = ac1;
            ((float4*)(pvred + sr * 1024 + 512))[d4] = ac2;
            ((float4*)(pvred + sr * 1024 + 768))[d4] = ac3;
            __syncthreads();
            for (int o = t; o < 1024; o += 256) {
                float v = pvred[o] + pvred[1024 + o] + pvred[2048 + o] + pvred[3072 + o];
                POP[(size_t)bid * 1024 + o] = v;
            }
        }
        gg.sync();

        // ---------- wo phase: 288 units ----------
        {
            float* hinv = sm;
            float* xred = sm + 8;
            float* xl = sm + 272;
            float* red4 = sm + 312;
            float* wored = sm + 320;
            for (int h = 0; h < NH; ++h) {
                float v = (t < 128) ? SPS[t * NH + h] : 0.f;
                float tot = bsum(v, red4);
                if (t == 0) hinv[h] = 1.f / tot;
            }
            __syncthreads();
            const float* Wo_l = p.Wo + (size_t)l * 1024 * DM;
            for (int u = bid; u < 288; u += NB) {
                __syncthreads();
                int cgp = u % 9, kc = u / 9;
                int i0 = kc * 32;
                { int li = t & 31, bg = t >> 5;
                  float a = 0.f;
                  for (int b = bg * 16; b < bg * 16 + 16; ++b) a += POP[(size_t)b * 1024 + i0 + li];
                  xred[bg * 32 + li] = a; }
                __syncthreads();
                if (t < 32) {
                    float a = 0.f;
#pragma unroll
                    for (int bg = 0; bg < 8; ++bg) a += xred[bg * 32 + t];
                    xl[t] = a * hinv[(i0 + t) >> 8];
                }
                __syncthreads();
                int col = cgp * 128 + (t & 127);
                int kh = t >> 7;
                float acc = 0.f;
#pragma unroll
                for (int r = 0; r < 16; ++r) {
                    int li = kh * 16 + r;
                    acc += xl[li] * Wo_l[(size_t)(i0 + li) * DM + col];
                }
                wored[t] = acc;
                __syncthreads();
                if (t < 128) atomicAdd(&AP[cgp * 128 + t], wored[t] + wored[128 + t]);
            }
        }
        gg.sync();

        // ---------- gu phase: 486 units ----------
        {
            float* xv = sm; float* red4 = sm + 1152; float* gred = sm + 1184;
            float ss = 0.f;
            for (int i = t; i < DM; i += 256) { float a = AP[i]; ss += a * a; }
            ss = bsum(ss, red4);
            float inv = 1.f / sqrtf(ss / DM + EPSV);
            const float* wpa = p.w_pa + l * DM;
            for (int i = t; i < DM; i += 256) xv[i] = HIN[i] + wpa[i] * AP[i] * inv;
            __syncthreads();
            if (bid == 0) for (int i = t; i < DM; i += 256) HM[i] = xv[i];
            float s2 = 0.f;
            for (int i = t; i < DM; i += 256) { float v = xv[i]; s2 += v * v; }
            s2 = bsum(s2, red4);
            float inv2 = 1.f / sqrtf(s2 / DM + EPSV);
            const float* wpf = p.w_pf + l * DM;
            for (int i = t; i < DM; i += 256) xv[i] = wpf[i] * xv[i] * inv2;
            __syncthreads();
            for (int u = bid; u < 486; u += NB) {
                __syncthreads();
                int cgi = u % 54, kc = u / 54;
                bool isU = cgi >= 27;
                int cgp = isU ? cgi - 27 : cgi;
                const float* W = (isU ? p.Wu : p.Wg) + (size_t)l * DM * FF;
                int f4c = t & 63, ks = t >> 6;
                int colf = cgp * 64 + f4c;
                int i0 = kc * 128 + ks * 32;
                float4 acc = {0,0,0,0};
#pragma unroll 4
                for (int r = 0; r < 32; ++r) {
                    float xs = xv[i0 + r];
                    float4 w = ((const float4*)(W + (size_t)(i0 + r) * FF))[colf];
                    acc.x += xs * w.x; acc.y += xs * w.y; acc.z += xs * w.z; acc.w += xs * w.w;
                }
                ((float4*)gred)[ks * 64 + f4c] = acc;
                __syncthreads();
                if (ks == 0) {
                    float4 r0 = ((float4*)gred)[f4c],       r1 = ((float4*)gred)[64 + f4c],
                           r2 = ((float4*)gred)[128 + f4c], r3 = ((float4*)gred)[192 + f4c];
                    float* dst = GU + (isU ? FF : 0) + colf * 4;
                    atomicAdd(dst + 0, r0.x + r1.x + r2.x + r3.x);
                    atomicAdd(dst + 1, r0.y + r1.y + r2.y + r3.y);
                    atomicAdd(dst + 2, r0.z + r1.z + r2.z + r3.z);
                    atomicAdd(dst + 3, r0.w + r1.w + r2.w + r3.w);
                }
            }
        }
        gg.sync();

        // ---------- wd phase: 486 units ----------
        {
            float* m = sm;
            float* wred = sm + 128;
            const float* Wd_l = p.Wd + (size_t)l * FF * DM;
            for (int u = bid; u < 486; u += NB) {
                __syncthreads();
                int cgp = u % 9, kc = u / 9;
                int i0 = kc * 128;
                if (t < 128) {
                    float g = GU[i0 + t], uu = GU[FF + i0 + t];
                    float gl = 0.5f * g * (1.f + tanhf(0.7978845608028654f * (g + 0.044715f * g * g * g)));
                    m[t] = gl * uu;
                }
                __syncthreads();
                int f4c = t & 31, ks = t >> 5;
                float4 acc = {0,0,0,0};
#pragma unroll 4
                for (int r = 0; r < 16; ++r) {
                    int li = ks * 16 + r;
                    float xs = m[li];
                    float4 w = ((const float4*)(Wd_l + (size_t)(i0 + li) * DM))[cgp * 32 + f4c];
                    acc.x += xs * w.x; acc.y += xs * w.y; acc.z += xs * w.z; acc.w += xs * w.w;
                }
                ((float4*)wred)[ks * 32 + f4c] = acc;
                __syncthreads();
                if (ks == 0) {
                    float sx = 0, sy = 0, sz = 0, sw = 0;
#pragma unroll
                    for (int k2 = 0; k2 < 8; ++k2) {
                        float4 r = ((float4*)wred)[k2 * 32 + f4c];
                        sx += r.x; sy += r.y; sz += r.z; sw += r.w;
                    }
                    float* dst = DP + cgp * 128 + f4c * 4;
                    atomicAdd(dst + 0, sx); atomicAdd(dst + 1, sy);
                    atomicAdd(dst + 2, sz); atomicAdd(dst + 3, sw);
                }
            }
        }
        gg.sync();
    }
}

// ==================== shared tail + fallback kernels (round-2 verbatim) ====================
__device__ __forceinline__ float block_sum256(float v, float* red4) {
#pragma unroll
    for (int off = 32; off; off >>= 1) v += __shfl_xor(v, off);
    int t = threadIdx.x;
    if ((t & 63) == 0) red4[t >> 6] = v;
    __syncthreads();
    float r = red4[0] + red4[1] + red4[2] + red4[3];
    __syncthreads();
    return r;
}

__global__ __launch_bounds__(256) void gk_copy(const float* __restrict__ kc,
                                               const float* __restrict__ vc,
                                               float* __restrict__ keys,
                                               float* __restrict__ vals) {
    int b = blockIdx.x;
    if (b < 24576) {
        int row = b >> 4;
        int s = ((b & 15) << 8) + threadIdx.x;
        if (s < HIST) keys[(size_t)row * SEQ + s] = kc[(size_t)row * HIST + s];
    } else {
        int r = (b - 24576) * 4 + (threadIdx.x >> 6);
        int d4 = threadIdx.x & 63;
        if (r < LNUM * HIST) {
            int l = r / HIST, sI = r - l * HIST;
            ((float4*)(vals + ((size_t)l * SEQ + sI) * DHEAD))[d4] =
                ((const float4*)(vc + (size_t)r * DHEAD))[d4];
        }
    }
}

__global__ __launch_bounds__(256) void gk_qkv(
    const float* __restrict__ Wq, const float* __restrict__ Wk, const float* __restrict__ Wv,
    const float* __restrict__ w_in, const float* __restrict__ w_pof_prev,
    const float* __restrict__ hprev, const float* __restrict__ dprev,
    const int* __restrict__ ids, const int* __restrict__ tbl,
    const float* __restrict__ escale, const float* __restrict__ ezp,
    float* __restrict__ hin_out, float* __restrict__ qkv_out, int has_prev) {
    __shared__ float xv[DM];
    __shared__ float red4[4];
    int t = threadIdx.x;
    if (has_prev) {
        float ss = 0.f;
        for (int i = t; i < DM; i += 256) { float d = dprev[i]; ss += d * d; }
        ss = block_sum256(ss, red4);
        float inv = 1.f / sqrtf(ss / DM + EPSV);
        for (int i = t; i < DM; i += 256)
            xv[i] = hprev[i] + w_pof_prev[i] * dprev[i] * inv;
    } else {
        int tok = ids[0];
        float sc = escale[tok], z = ezp[tok];
        const int* row = tbl + (size_t)tok * DM;
        for (int i = t; i < DM; i += 256) xv[i] = (float)row[i] * sc + z;
    }
    __syncthreads();
    if (blockIdx.x == 0 && blockIdx.y == 0)
        for (int i = t; i < DM; i += 256) hin_out[i] = xv[i];
    float ss = 0.f;
    for (int i = t; i < DM; i += 256) { float v = xv[i]; ss += v * v; }
    ss = block_sum256(ss, red4);
    float inv = 1.f / sqrtf(ss / DM + EPSV);
    for (int i = t; i < DM; i += 256) xv[i] = w_in[i] * xv[i] * inv;
    __syncthreads();

    int j = blockIdx.x * 256 + t;
    const float* W; int jj, ncol;
    if (j < 1024)      { W = Wq; jj = j;        ncol = 1024; }
    else if (j < 1280) { W = Wk; jj = j - 1024; ncol = 256; }
    else               { W = Wv; jj = j - 1280; ncol = 256; }
    int i0 = blockIdx.y * 36;
    float acc = 0.f;
#pragma unroll 4
    for (int ii = 0; ii < 36; ++ii)
        acc += xv[i0 + ii] * W[(size_t)(i0 + ii) * ncol + jj];
    atomicAdd(&qkv_out[j], acc);
}

__global__ __launch_bounds__(256) void gk_attn(
    const float* __restrict__ qkv, const float* __restrict__ w_qn,
    const float* __restrict__ w_kn, const int* __restrict__ attn_flag,
    float* __restrict__ keys_l, float* __restrict__ vals_l,
    float* __restrict__ po_part, float* __restrict__ sum_part, float rope_base) {
    __shared__ float lq[NH * DHEAD];
    __shared__ float lqf[NH * DHEAD];
    __shared__ float lkn[DHEAD];
    __shared__ float lkf[DHEAD];
    __shared__ float lv[DHEAD];
    __shared__ float lp[NH * 32];
    __shared__ float red4[4];
    int t = threadIdx.x;
    int s0 = blockIdx.x * 32;
    bool last = (blockIdx.x == gridDim.x - 1);

    int jm = t & 127;
    float theta = powf(rope_base, -(float)(2 * jm) / 256.f);
    float ang = 4095.f * theta;
    float c = __half2float(__float2half(cosf(ang)));
    float s = __half2float(__float2half(sinf(ang)));

    for (int h = 0; h < NH; ++h) lq[h * 256 + t] = qkv[h * 256 + t];
    lkn[t] = qkv[1024 + t];
    lv[t]  = qkv[1280 + t];
    __syncthreads();
    for (int h = 0; h < NH; ++h) {
        float v = lq[h * 256 + t];
        float ss = block_sum256(v * v, red4);
        float inv = 1.f / sqrtf(ss / 256.f + EPSV);
        float qn = w_qn[t] * v * inv;
        lq[h * 256 + t] = qn;
        __syncthreads();
        float partner = (t < 128) ? -lq[h * 256 + t + 128] : lq[h * 256 + t - 128];
        lqf[h * 256 + t] = qn * c + partner * s;
    }
    {
        float v = lkn[t];
        float ss = block_sum256(v * v, red4);
        float inv = 1.f / sqrtf(ss / 256.f + EPSV);
        float kn = w_kn[t] * v * inv;
        lkn[t] = kn;
        __syncthreads();
        float partner = (t < 128) ? -lkn[t + 128] : lkn[t - 128];
        lkf[t] = kn * c + partner * s;
    }
    __syncthreads();
    if (last) {
        keys_l[(size_t)t * SEQ + (SEQ - 1)] = lkf[t];
        vals_l[(size_t)(SEQ - 1) * DHEAD + t] = lv[t];
    }
    int sl = t & 31, dc = t >> 5;
    int sg = s0 + sl;
    bool self = last && (sl == 31);
    float a0 = 0, a1 = 0, a2 = 0, a3 = 0;
#pragma unroll 4
    for (int dd = 0; dd < 32; ++dd) {
        int d = dc * 32 + dd;
        float kv = self ? lkf[d] : keys_l[(size_t)d * SEQ + sg];
        a0 += lqf[0 * 256 + d] * kv;
        a1 += lqf[1 * 256 + d] * kv;
        a2 += lqf[2 * 256 + d] * kv;
        a3 += lqf[3 * 256 + d] * kv;
    }
    __syncthreads();
    lq[0 * 256 + t] = a0; lq[1 * 256 + t] = a1; lq[2 * 256 + t] = a2; lq[3 * 256 + t] = a3;
    __syncthreads();
    if (t < 32) {
        int af = attn_flag[0];
        float mk = (s0 + t > 0) ? -128.f * (float)af : 0.f;
        for (int h = 0; h < NH; ++h) {
            float sc_ = 0.f;
#pragma unroll
            for (int d8 = 0; d8 < 8; ++d8) sc_ += lq[h * 256 + d8 * 32 + t];
            lp[h * 32 + t] = expf(sc_ + mk);
        }
    }
    __syncthreads();
    if (t < NH) {
        float su = 0.f;
        for (int i = 0; i < 32; ++i) su += lp[t * 32 + i];
        sum_part[blockIdx.x * NH + t] = su;
    }
    float p0 = 0, p1 = 0, p2 = 0, p3 = 0;
#pragma unroll 4
    for (int ss_ = 0; ss_ < 32; ++ss_) {
        float v = (last && ss_ == 31) ? lv[t] : vals_l[(size_t)(s0 + ss_) * DHEAD + t];
        p0 += lp[0 * 32 + ss_] * v;
        p1 += lp[1 * 32 + ss_] * v;
        p2 += lp[2 * 32 + ss_] * v;
        p3 += lp[3 * 32 + ss_] * v;
    }
    float* po = po_part + (size_t)blockIdx.x * NH * DHEAD;
    po[0 * 256 + t] = p0; po[1 * 256 + t] = p1; po[2 * 256 + t] = p2; po[3 * 256 + t] = p3;
}

__global__ __launch_bounds__(256) void gk_wo(
    const float* __restrict__ po_part, const float* __restrict__ sum_part,
    const float* __restrict__ Wo_l, float* __restrict__ aproj) {
    __shared__ float x[64];
    __shared__ float hinv[NH];
    __shared__ float red4[4];
    int t = threadIdx.x;
    for (int h = 0; h < NH; ++h) {
        float v = (t < 128) ? sum_part[t * NH + h] : 0.f;
        float tot = block_sum256(v, red4);
        if (t == 0) hinv[h] = 1.f / tot;
    }
    __syncthreads();
    int i0 = blockIdx.y * 64;
    if (t < 64) {
        float a = 0.f;
#pragma unroll 8
        for (int b = 0; b < 128; ++b) a += po_part[(size_t)b * 1024 + i0 + t];
        x[t] = a * hinv[(i0 + t) >> 8];
    }
    __syncthreads();
    int j = blockIdx.x * 256 + t;
    if (j < DM) {
        float acc = 0.f;
#pragma unroll 4
        for (int ii = 0; ii < 64; ++ii)
            acc += x[ii] * Wo_l[(size_t)(i0 + ii) * DM + j];
        atomicAdd(&aproj[j], acc);
    }
}

__global__ __launch_bounds__(256) void gk_gu(
    const float* __restrict__ Wg_l, const float* __restrict__ Wu_l,
    const float* __restrict__ w_pa, const float* __restrict__ w_pf,
    const float* __restrict__ hin, const float* __restrict__ aproj,
    float* __restrict__ hmid_out, float* __restrict__ gup) {
    __shared__ float xv[DM];
    __shared__ float red4[4];
    int t = threadIdx.x;
    float ss = 0.f;
    for (int i = t; i < DM; i += 256) { float a = aproj[i]; ss += a * a; }
    ss = block_sum256(ss, red4);
    float inv = 1.f / sqrtf(ss / DM + EPSV);
    for (int i = t; i < DM; i += 256) xv[i] = hin[i] + w_pa[i] * aproj[i] * inv;
    __syncthreads();
    if (blockIdx.x == 0 && blockIdx.y == 0)
        for (int i = t; i < DM; i += 256) hmid_out[i] = xv[i];
    float s2 = 0.f;
    for (int i = t; i < DM; i += 256) { float v = xv[i]; s2 += v * v; }
    s2 = block_sum256(s2, red4);
    float inv2 = 1.f / sqrtf(s2 / DM + EPSV);
    for (int i = t; i < DM; i += 256) xv[i] = w_pf[i] * xv[i] * inv2;
    __syncthreads();

    int j2 = blockIdx.x * 256 + t;
    const float2* W2; int jj2; float* dst;
    if (j2 < FF / 2) { W2 = (const float2*)Wg_l; jj2 = j2;
                       dst = gup + (size_t)blockIdx.y * 2 * FF + 2 * j2; }
    else             { W2 = (const float2*)Wu_l; jj2 = j2 - FF / 2;
                       dst = gup + (size_t)blockIdx.y * 2 * FF + FF + 2 * (j2 - FF / 2); }
    int i0 = blockIdx.y * 72;
    float ax = 0.f, ay = 0.f;
#pragma unroll 4
    for (int ii = 0; ii < 72; ++ii) {
        float xs = xv[i0 + ii];
        float2 w = W2[(size_t)(i0 + ii) * (FF / 2) + jj2];
        ax += xs * w.x; ay += xs * w.y;
    }
    dst[0] = ax; dst[1] = ay;
}

__global__ __launch_bounds__(256) void gk_wd(const float* __restrict__ gup,
                                             const float* __restrict__ Wd_l,
                                             float* __restrict__ dproj) {
    __shared__ float m[108];
    int t = threadIdx.x;
    int i0 = blockIdx.y * 108;
    if (t < 108) {
        float g = 0.f, u = 0.f;
#pragma unroll
        for (int p = 0; p < 16; ++p) {
            g += gup[(size_t)p * 2 * FF + i0 + t];
            u += gup[(size_t)p * 2 * FF + FF + i0 + t];
        }
        float gl = 0.5f * g * (1.f + tanhf(0.7978845608028654f * (g + 0.044715f * g * g * g)));
        m[t] = gl * u;
    }
    __syncthreads();
    int j = blockIdx.x * 256 + t;
    if (j < DM) {
        float acc = 0.f;
#pragma unroll 4
        for (int ii = 0; ii < 108; ++ii)
            acc += m[ii] * Wd_l[(size_t)(i0 + ii) * DM + j];
        atomicAdd(&dproj[j], acc);
    }
}

__global__ __launch_bounds__(256) void gk_logits(
    const float* __restrict__ W_lm, const float* __restrict__ w_pof5,
    const float* __restrict__ w_fin, const float* __restrict__ hmid5,
    const float* __restrict__ dproj5, float* __restrict__ lgp) {
    __shared__ float xv[DM];
    __shared__ float red4[4];
    int t = threadIdx.x;
    float ss = 0.f;
    for (int i = t; i < DM; i += 256) { float d = dproj5[i]; ss += d * d; }
    ss = block_sum256(ss, red4);
    float inv = 1.f / sqrtf(ss / DM + EPSV);
    for (int i = t; i < DM; i += 256) xv[i] = hmid5[i] + w_pof5[i] * dproj5[i] * inv;
    __syncthreads();
    float s2 = 0.f;
    for (int i = t; i < DM; i += 256) { float v = xv[i]; s2 += v * v; }
    s2 = block_sum256(s2, red4);
    float inv2 = 1.f / sqrtf(s2 / DM + EPSV);
    for (int i = t; i < DM; i += 256) xv[i] = w_fin[i] * xv[i] * inv2;
    __syncthreads();

    int j2 = blockIdx.x * 256 + t;
    int i0 = blockIdx.y * 192;
    const float2* W2 = (const float2*)W_lm;
    float ax = 0.f, ay = 0.f;
#pragma unroll 4
    for (int ii = 0; ii < 192; ++ii) {
        float xs = xv[i0 + ii];
        float2 w = W2[(size_t)(i0 + ii) * (VOC / 2) + j2];
        ax += xs * w.x; ay += xs * w.y;
    }
    float* dst = lgp + (size_t)blockIdx.y * VOC + 2 * j2;
    dst[0] = ax; dst[1] = ay;
}

__global__ __launch_bounds__(256) void gk_amax1(const float* __restrict__ lgp,
                                                float* __restrict__ pv, float* __restrict__ pi) {
    __shared__ float rv[256];
    __shared__ int ri[256];
    int t = threadIdx.x;
    int c1 = blockIdx.x * 512 + t, c2 = c1 + 256;
    float v1 = 0.f, v2 = 0.f;
#pragma unroll
    for (int p = 0; p < 6; ++p) {
        v1 += lgp[(size_t)p * VOC + c1];
        v2 += lgp[(size_t)p * VOC + c2];
    }
    float bv; int bi;
    if (v1 >= v2) { bv = v1; bi = c1; } else { bv = v2; bi = c2; }
    rv[t] = bv; ri[t] = bi; __syncthreads();
    for (int off = 128; off > 0; off >>= 1) {
        if (t < off) {
            float ov = rv[t + off]; int oi = ri[t + off];
            if (ov > rv[t] || (ov == rv[t] && oi < ri[t])) { rv[t] = ov; ri[t] = oi; }
        }
        __syncthreads();
    }
    if (t == 0) { pv[blockIdx.x] = rv[0]; pi[blockIdx.x] = (float)ri[0]; }
}

__global__ __launch_bounds__(128) void gk_amax2(const float* __restrict__ pv,
                                                const float* __restrict__ pi,
                                                float* __restrict__ tok_out) {
    __shared__ float rv[128];
    __shared__ int ri[128];
    int t = threadIdx.x;
    rv[t] = pv[t]; ri[t] = (int)pi[t]; __syncthreads();
    for (int off = 64; off > 0; off >>= 1) {
        if (t < off) {
            float ov = rv[t + off]; int oi = ri[t + off];
            if (ov > rv[t] || (ov == rv[t] && oi < ri[t])) { rv[t] = ov; ri[t] = oi; }
        }
        __syncthreads();
    }
    if (t == 0) tok_out[0] = (float)ri[0];
}

// ==================== host launcher ====================
extern "C" void kernel_launch(void* const* d_in, const int* in_sizes, int n_in,
                              void* d_out, int out_size, void* d_ws, size_t ws_size,
                              hipStream_t stream) {
    P p;
    p.ids   = (const int*)d_in[0];
    p.aflag = (const int*)d_in[1];
    p.kc    = (const float*)d_in[2];
    p.vc    = (const float*)d_in[3];
    p.tbl   = (const int*)d_in[4];
    p.esc   = (const float*)d_in[5];
    p.ezp   = (const float*)d_in[6];
    p.w_in  = (const float*)d_in[7];
    p.w_qn  = (const float*)d_in[8];
    p.w_kn  = (const float*)d_in[9];
    p.Wq    = (const float*)d_in[10];
    p.Wk    = (const float*)d_in[11];
    p.Wv    = (const float*)d_in[12];
    p.Wo    = (const float*)d_in[13];
    p.w_pa  = (const float*)d_in[14];
    p.w_pf  = (const float*)d_in[15];
    p.w_pof = (const float*)d_in[16];
    p.Wg    = (const float*)d_in[17];
    p.Wu    = (const float*)d_in[18];
    p.Wd    = (const float*)d_in[19];
    p.w_fin = (const float*)d_in[20];
    p.Wlm   = (const float*)d_in[21];
    p.keys  = (float*)d_out;
    p.vals  = p.keys + (size_t)LNUM * DHEAD * SEQ;
    p.tok   = p.vals + (size_t)LNUM * SEQ * DHEAD;
    p.ws    = (float*)d_ws;
    float* ws = (float*)d_ws;

    void* args[] = { &p };
    hipError_t err = hipLaunchCooperativeKernel((void*)mega, dim3(NB), dim3(256), args, 0, stream);

    if (err == hipSuccess) {
        // coop path tail
        gk_logits<<<dim3(128, 6), 256, 0, stream>>>(
            p.Wlm, p.w_pof + (size_t)5 * DM, p.w_fin,
            ws + HM_O + (size_t)5 * DM, ws + DP_O + (size_t)5 * DM, ws + LGP_O);
        gk_amax1<<<128, 256, 0, stream>>>(ws + LGP_O, ws + AMV_O, ws + AMI_O);
        gk_amax2<<<1, 128, 0, stream>>>(ws + AMV_O, ws + AMI_O, p.tok);
    } else {
        // fallback: round-2 verbatim multi-kernel path
        hipMemsetAsync(ws, 0, F_ZEND * sizeof(float), stream);
        gk_copy<<<24576 + 6144, 256, 0, stream>>>(p.kc, p.vc, p.keys, p.vals);
        for (int l = 0; l < LNUM; ++l) {
            float* QKVl = ws + F_QKV_O + (size_t)l * 1536;
            float* APl  = ws + F_AP_O + (size_t)l * DM;
            float* DPl  = ws + F_DP_O + (size_t)l * DM;
            float* HINl = ws + F_HIN_O + (size_t)l * DM;
            float* HMl  = ws + F_HM_O + (size_t)l * DM;
            float* keys_l = p.keys + (size_t)l * DHEAD * SEQ;
            float* vals_l = p.vals + (size_t)l * SEQ * DHEAD;

            gk_qkv<<<dim3(6, 32), 256, 0, stream>>>(
                p.Wq + (size_t)l * DM * 1024, p.Wk + (size_t)l * DM * 256,
                p.Wv + (size_t)l * DM * 256, p.w_in + (size_t)l * DM,
                p.w_pof + (size_t)(l ? l - 1 : 0) * DM,
                (l ? ws + F_HM_O + (size_t)(l - 1) * DM : nullptr),
                (l ? ws + F_DP_O + (size_t)(l - 1) * DM : nullptr),
                p.ids, p.tbl, p.esc, p.ezp,
                HINl, QKVl, (l > 0) ? 1 : 0);

            gk_attn<<<128, 256, 0, stream>>>(
                QKVl, p.w_qn + (size_t)l * DHEAD, p.w_kn + (size_t)l * DHEAD,
                p.aflag, keys_l, vals_l, ws + F_POP_O, ws + F_SPS_O,
                ((l % 6) != 5) ? 1000000.0f : 10000.0f);

            gk_wo<<<dim3(5, 16), 256, 0, stream>>>(
                ws + F_POP_O, ws + F_SPS_O, p.Wo + (size_t)l * 1024 * DM, APl);

            gk_gu<<<dim3(27, 16), 256, 0, stream>>>(
                p.Wg + (size_t)l * DM * FF, p.Wu + (size_t)l * DM * FF,
                p.w_pa + (size_t)l * DM, p.w_pf + (size_t)l * DM, HINl, APl, HMl, ws + F_GUP_O);

            gk_wd<<<dim3(5, 64), 256, 0, stream>>>(ws + F_GUP_O, p.Wd + (size_t)l * FF * DM, DPl);
        }
        gk_logits<<<dim3(128, 6), 256, 0, stream>>>(
            p.Wlm, p.w_pof + (size_t)5 * DM, p.w_fin,
            ws + F_HM_O + (size_t)5 * DM, ws + F_DP_O + (size_t)5 * DM, ws + F_LGP_O);
        gk_amax1<<<128, 256, 0, stream>>>(ws + F_LGP_O, ws + F_AMV_O, ws + F_AMI_O);
        gk_amax2<<<1, 128, 0, stream>>>(ws + F_AMV_O, ws + F_AMI_O, p.tok);
    }
}